// Round 4
// baseline (113144.604 us; speedup 1.0000x reference)
//
#include <hip/hip_runtime.h>
#include <hip/hip_bf16.h>

#define S_ 1024
#define B_ 64
#define E_ 512
#define H_ 512
#define G3_ 1536

typedef __hip_bfloat16 bf16;

// ---------- dtype helpers ----------
template<typename T> struct alignas(4*sizeof(T)) V4 { T v[4]; };

__device__ __forceinline__ float toF(float x){ return x; }
__device__ __forceinline__ float toF(bf16 x){ return __bfloat162float(x); }
__device__ __forceinline__ void storeF(float* p, float v){ *p = v; }
__device__ __forceinline__ void storeF(bf16* p, float v){ *p = __float2bfloat16(v); }

// ------------------------------ signal kernel -------------------------------
__global__ __launch_bounds__(256)
void signal_kernel(float* __restrict__ out, long n, float v)
{
  long i = (long)blockIdx.x * 256 + threadIdx.x;
  const long stride = (long)gridDim.x * 256;
  for (; i < n; i += stride) out[i] = v;
}

// ------------------------------- tiled GEMM ---------------------------------
// C[m][n] = sum_k A[m][k] * W[n][k]
// AMODE 0: A[m][k] = emb[src[m]][k] * (src[m]!=0)            (fp32 gather)
// AMODE 1: A[m][k] = k<H ? Af[m*rsF+k] (HT) : Ab[m*rsB+k-H] (XT)
// EPI 0: store raw XT to Cx (row stride N). EPI 1: store f32 tanh(acc+bias).
template<typename XT, typename HT, int AMODE, int EPI>
__global__ __launch_bounds__(256, 2)
void gemm_tile(const int* __restrict__ src, const float* __restrict__ emb,
               const HT* __restrict__ Af, int rsF, const XT* __restrict__ Ab, int rsB,
               const float* __restrict__ W,
               XT* __restrict__ Cx, float* __restrict__ Cf, const float* __restrict__ bias,
               int N, int K)
{
  __shared__ float As[16][132];
  __shared__ float Bs[16][132];
  __shared__ int s_tok[128];
  const int m0 = blockIdx.x * 128;
  const int n0 = blockIdx.y * 128;
  const int tid = threadIdx.x;
  const int tx = tid & 15, ty = tid >> 4;

  if constexpr (AMODE == 0) {
    if (tid < 128) s_tok[tid] = src[m0 + tid];
  }
  __syncthreads();

  float acc[8][8];
  #pragma unroll
  for (int i = 0; i < 8; ++i)
    #pragma unroll
    for (int j = 0; j < 8; ++j) acc[i][j] = 0.f;

  for (int k0 = 0; k0 < K; k0 += 16) {
    #pragma unroll
    for (int i = 0; i < 2; ++i) {
      const int f = tid * 2 + i;
      const int r = f >> 2, kq = f & 3;
      const int kk = k0 + kq * 4;
      float a0, a1, a2, a3;
      if constexpr (AMODE == 0) {
        const int tok = s_tok[r];
        if (tok != 0) {
          float4 v = *(const float4*)(emb + (size_t)tok * E_ + kk);
          a0 = v.x; a1 = v.y; a2 = v.z; a3 = v.w;
        } else { a0 = a1 = a2 = a3 = 0.f; }
      } else {
        if (kk < H_) {
          V4<HT> v = *(const V4<HT>*)(Af + (size_t)(m0 + r) * rsF + kk);
          a0 = toF(v.v[0]); a1 = toF(v.v[1]); a2 = toF(v.v[2]); a3 = toF(v.v[3]);
        } else {
          V4<XT> v = *(const V4<XT>*)(Ab + (size_t)(m0 + r) * rsB + (kk - H_));
          a0 = toF(v.v[0]); a1 = toF(v.v[1]); a2 = toF(v.v[2]); a3 = toF(v.v[3]);
        }
      }
      As[kq*4+0][r] = a0; As[kq*4+1][r] = a1; As[kq*4+2][r] = a2; As[kq*4+3][r] = a3;
      float4 b = *(const float4*)(W + (size_t)(n0 + r) * K + kk);
      Bs[kq*4+0][r] = b.x; Bs[kq*4+1][r] = b.y; Bs[kq*4+2][r] = b.z; Bs[kq*4+3][r] = b.w;
    }
    __syncthreads();
    #pragma unroll
    for (int k = 0; k < 16; ++k) {
      float4 ra0 = *(const float4*)&As[k][ty*8];
      float4 ra1 = *(const float4*)&As[k][ty*8+4];
      float4 rb0 = *(const float4*)&Bs[k][tx*8];
      float4 rb1 = *(const float4*)&Bs[k][tx*8+4];
      float fa[8] = {ra0.x,ra0.y,ra0.z,ra0.w,ra1.x,ra1.y,ra1.z,ra1.w};
      float fb[8] = {rb0.x,rb0.y,rb0.z,rb0.w,rb1.x,rb1.y,rb1.z,rb1.w};
      #pragma unroll
      for (int i = 0; i < 8; ++i)
        #pragma unroll
        for (int j = 0; j < 8; ++j) acc[i][j] += fa[i] * fb[j];
    }
    __syncthreads();
  }

  if constexpr (EPI == 0) {
    #pragma unroll
    for (int i = 0; i < 8; ++i) {
      XT* crow = Cx + (size_t)(m0 + ty*8 + i) * N + n0 + tx*8;
      V4<XT> o0, o1;
      #pragma unroll
      for (int c = 0; c < 4; ++c) { storeF(&o0.v[c], acc[i][c]); storeF(&o1.v[c], acc[i][4+c]); }
      ((V4<XT>*)crow)[0] = o0; ((V4<XT>*)crow)[1] = o1;
    }
  } else {
    float bj[8];
    #pragma unroll
    for (int j = 0; j < 8; ++j) bj[j] = bias[n0 + tx*8 + j];
    #pragma unroll
    for (int i = 0; i < 8; ++i) {
      float* crow = Cf + (size_t)(m0 + ty*8 + i) * N + n0 + tx*8;
      float4 o0, o1;
      o0.x = tanhf(acc[i][0]+bj[0]); o0.y = tanhf(acc[i][1]+bj[1]);
      o0.z = tanhf(acc[i][2]+bj[2]); o0.w = tanhf(acc[i][3]+bj[3]);
      o1.x = tanhf(acc[i][4]+bj[4]); o1.y = tanhf(acc[i][5]+bj[5]);
      o1.z = tanhf(acc[i][6]+bj[6]); o1.w = tanhf(acc[i][7]+bj[7]);
      ((float4*)crow)[0] = o0; ((float4*)crow)[1] = o1;
    }
  }
}

// -------- in-place LayerNorm per 512-chunk (3 gates) + gain/bias fold -------
template<typename XT>
__global__ __launch_bounds__(256)
void ln3_kernel(XT* __restrict__ xp, const float* __restrict__ g,
                const float* __restrict__ be, const float* __restrict__ b)
{
  const size_t base = (size_t)blockIdx.x * G3_;
  const int t = threadIdx.x;
  float v[6];
  #pragma unroll
  for (int gg = 0; gg < 3; ++gg) {
    v[gg*2+0] = toF(xp[base + gg*512 + t]);
    v[gg*2+1] = toF(xp[base + gg*512 + 256 + t]);
  }
  float s0 = v[0]+v[1], q0 = v[0]*v[0]+v[1]*v[1];
  float s1 = v[2]+v[3], q1 = v[2]*v[2]+v[3]*v[3];
  float s2 = v[4]+v[5], q2 = v[4]*v[4]+v[5]*v[5];
  #pragma unroll
  for (int m = 1; m < 64; m <<= 1) {
    s0 += __shfl_xor(s0, m); q0 += __shfl_xor(q0, m);
    s1 += __shfl_xor(s1, m); q1 += __shfl_xor(q1, m);
    s2 += __shfl_xor(s2, m); q2 += __shfl_xor(q2, m);
  }
  __shared__ float red[4][6];
  __shared__ float stat[6];
  const int wid = t >> 6, lane = t & 63;
  if (lane == 0) { red[wid][0]=s0; red[wid][1]=q0; red[wid][2]=s1; red[wid][3]=q1; red[wid][4]=s2; red[wid][5]=q2; }
  __syncthreads();
  if (t < 6) stat[t] = red[0][t] + red[1][t] + red[2][t] + red[3][t];
  __syncthreads();
  #pragma unroll
  for (int gg = 0; gg < 3; ++gg) {
    const float mu  = stat[gg*2]   * (1.f/512.f);
    const float var = stat[gg*2+1] * (1.f/512.f) - mu*mu;
    const float sc  = rsqrtf(var + 1e-5f);
    #pragma unroll
    for (int u = 0; u < 2; ++u) {
      const int c = gg*512 + u*256 + t;
      storeF(&xp[base + c], (v[gg*2+u] - mu) * sc * g[c] + be[c] + b[c]);
    }
  }
}

// --------------------------- persistent scan kernel -------------------------
// Blocks: (dir, batch-group bg of 16 b, j-slice js of 16 j). W_hh in VGPRs.
// Cross-block exchange: ACQUIRE spin + all-thread __threadfence() after each
// barrier (per-wave L1 invalidate); release fence + __syncthreads before each
// counter increment. hidden-state outputs are f32 now.
template<typename XT, typename HT>
__global__ __launch_bounds__(256, 1)
void scan_kernel(const XT* __restrict__ xp_f, const XT* __restrict__ xp_b,
                 const float* __restrict__ Whh_f, const float* __restrict__ Whh_b,
                 const float* __restrict__ gf, const float* __restrict__ bef, const float* __restrict__ bfv,
                 const float* __restrict__ gbv, const float* __restrict__ beb, const float* __restrict__ bbv,
                 float* __restrict__ hbuf, float* __restrict__ part,
                 unsigned* __restrict__ statcnt, unsigned* __restrict__ hcnt,
                 HT* __restrict__ houtF, int rsF, XT* __restrict__ houtB, int rsB,
                 float* __restrict__ outhid, int dirbase)
{
  __shared__ float hT[16][512];
  __shared__ float red[4][16][50];
  __shared__ float statL[96];

  const int bid = blockIdx.x;
  const int dir = dirbase + (bid >> 7);
  const int bi  = bid & 127;
  const int bg  = bi >> 5;
  const int js  = bi & 31;
  const int tid = threadIdx.x;
  const int jloc = tid & 15;
  const int pb   = tid >> 4;
  const int wid  = tid >> 6;
  const int ksw  = (tid >> 4) & 3;
  const int j    = js*16 + jloc;

  const XT* xp   = dir ? xp_b : xp_f;
  const float* W = dir ? Whh_b : Whh_f;
  const float* gv  = dir ? gbv : gf;
  const float* bev = dir ? beb : bef;
  const float* bv  = dir ? bbv : bfv;
  float* h = hbuf + dir * (B_ * H_);
  float* pp = part + ((size_t)((dir*4 + bg)*32 + js)) * 96;
  const float* pg = part + (size_t)(dir*4 + bg) * 32 * 96;
  unsigned* scnt = statcnt + dir*4 + bg;
  unsigned* hct  = hcnt    + dir*4 + bg;

  // W slice in registers; chunk order permuted by ksw -> bank-conflict-free
  // hT reads (4 ksw values hit 4 distinct bank groups each c-iteration).
  float w[3][32];
  {
    #pragma unroll
    for (int r = 0; r < 3; ++r) {
      const float* wr = W + (size_t)(r*H_ + j) * H_ + pb * 32;
      #pragma unroll
      for (int c = 0; c < 8; ++c) {
        const int p = (c + ksw*2) & 7;
        float4 f = *(const float4*)(wr + p*4);
        w[r][c*4+0] = f.x; w[r][c*4+1] = f.y; w[r][c*4+2] = f.z; w[r][c*4+3] = f.w;
      }
    }
  }
  const float gr0 = gv[j],            gr1 = gv[H_+j],               gr2 = gv[2*H_+j];
  const float gb0 = bev[j] + bv[j],   gb1 = bev[H_+j] + bv[H_+j],   gb2 = bev[2*H_+j] + bv[2*H_+j];

  int dead = 0;   // sticky: if a spin guard fires, stop spinning (terminate fast)

  for (int t = 0; t < S_; ++t) {
    // ---- barrier: h(t-1) complete ----
    if (tid == 0 && !dead) {
      const unsigned tgt = 32u * (unsigned)t;
      int guard = 0;
      while (__hip_atomic_load(hct, __ATOMIC_ACQUIRE, __HIP_MEMORY_SCOPE_AGENT) < tgt) {
        __builtin_amdgcn_s_sleep(2);
        if (++guard > (1 << 24)) { dead = 1; break; }
      }
    }
    __syncthreads();
    __threadfence();   // every wave: invalidate L1 before reading h

    // stage h tile (16 b x 512)
    {
      const int row = tid >> 4, seg = tid & 15;
      const float* hr = h + (size_t)(bg*16 + row) * H_;
      float4* dst = (float4*)&hT[row][0];
      #pragma unroll
      for (int i = 0; i < 8; ++i)
        dst[seg + i*16] = *(const float4*)(hr + seg*4 + i*64);
    }
    __syncthreads();

    // k-sliced dots for all 16 b of this group
    for (int b = 0; b < 16; ++b) {
      float a0 = 0.f, a1 = 0.f, a2 = 0.f;
      #pragma unroll
      for (int c = 0; c < 8; ++c) {
        const int p = (c + ksw*2) & 7;
        const float4 hv = *(const float4*)&hT[b][pb*32 + p*4];
        a0 += hv.x*w[0][c*4+0] + hv.y*w[0][c*4+1] + hv.z*w[0][c*4+2] + hv.w*w[0][c*4+3];
        a1 += hv.x*w[1][c*4+0] + hv.y*w[1][c*4+1] + hv.z*w[1][c*4+2] + hv.w*w[1][c*4+3];
        a2 += hv.x*w[2][c*4+0] + hv.y*w[2][c*4+1] + hv.z*w[2][c*4+2] + hv.w*w[2][c*4+3];
      }
      a0 += __shfl_xor(a0, 16); a0 += __shfl_xor(a0, 32);
      a1 += __shfl_xor(a1, 16); a1 += __shfl_xor(a1, 32);
      a2 += __shfl_xor(a2, 16); a2 += __shfl_xor(a2, 32);
      if (ksw == 0) {
        red[wid][jloc][b*3+0] = a0; red[wid][jloc][b*3+1] = a1; red[wid][jloc][b*3+2] = a2;
      }
    }
    __syncthreads();

    const float vr = red[0][jloc][pb*3+0]+red[1][jloc][pb*3+0]+red[2][jloc][pb*3+0]+red[3][jloc][pb*3+0];
    const float vz = red[0][jloc][pb*3+1]+red[1][jloc][pb*3+1]+red[2][jloc][pb*3+1]+red[3][jloc][pb*3+1];
    const float vn = red[0][jloc][pb*3+2]+red[1][jloc][pb*3+2]+red[2][jloc][pb*3+2]+red[3][jloc][pb*3+2];

    // LN-stat partials over this block's 16 j -> group buffer
    float sr = vr, qr = vr*vr, sz = vz, qz = vz*vz, sn = vn, qn = vn*vn;
    #pragma unroll
    for (int m = 1; m < 16; m <<= 1) {
      sr += __shfl_xor(sr, m); qr += __shfl_xor(qr, m);
      sz += __shfl_xor(sz, m); qz += __shfl_xor(qz, m);
      sn += __shfl_xor(sn, m); qn += __shfl_xor(qn, m);
    }
    if (jloc == 0) {
      pp[pb*6+0] = sr; pp[pb*6+1] = qr; pp[pb*6+2] = sz;
      pp[pb*6+3] = qz; pp[pb*6+4] = sn; pp[pb*6+5] = qn;
    }
    __threadfence();   // release: drain partial-stat stores
    __syncthreads();

    // ---- barrier: all 32 blocks' partials ready ----
    if (tid == 0 && !dead) {
      __hip_atomic_fetch_add(scnt, 1u, __ATOMIC_RELEASE, __HIP_MEMORY_SCOPE_AGENT);
      const unsigned tgt = 32u * (unsigned)(t + 1);
      int guard = 0;
      while (__hip_atomic_load(scnt, __ATOMIC_ACQUIRE, __HIP_MEMORY_SCOPE_AGENT) < tgt) {
        __builtin_amdgcn_s_sleep(2);
        if (++guard > (1 << 24)) { dead = 1; break; }
      }
    } else if (tid == 0) {
      __hip_atomic_fetch_add(scnt, 1u, __ATOMIC_RELEASE, __HIP_MEMORY_SCOPE_AGENT);
    }
    __syncthreads();
    __threadfence();   // every wave: invalidate L1 before reading partials

    if (tid < 96) {
      float a = 0.f;
      #pragma unroll 8
      for (int s2 = 0; s2 < 32; ++s2) a += pg[s2*96 + tid];
      statL[tid] = a;
    }
    __syncthreads();

    // gates + h update (thread owns (b=pb, j))
    {
      const int ab = bg*16 + pb;
      const float mur = statL[pb*6+0]*(1.f/512.f);
      const float var_r = statL[pb*6+1]*(1.f/512.f) - mur*mur;
      const float muz = statL[pb*6+2]*(1.f/512.f);
      const float var_z = statL[pb*6+3]*(1.f/512.f) - muz*muz;
      const float mun = statL[pb*6+4]*(1.f/512.f);
      const float var_n = statL[pb*6+5]*(1.f/512.f) - mun*mun;
      const float hr_ = (vr - mur) * rsqrtf(var_r + 1e-5f) * gr0 + gb0;
      const float hz_ = (vz - muz) * rsqrtf(var_z + 1e-5f) * gr1 + gb1;
      const float hn_ = (vn - mun) * rsqrtf(var_n + 1e-5f) * gr2 + gb2;
      const int tf = dir ? (S_ - 1 - t) : t;
      const size_t xbase = ((size_t)tf * B_ + ab) * G3_;
      const float xr = toF(xp[xbase + j]);
      const float xz = toF(xp[xbase + H_ + j]);
      const float xn = toF(xp[xbase + 2*H_ + j]);
      const float rg = 1.f / (1.f + __expf(-(xr + hr_)));
      const float zg = 1.f / (1.f + __expf(-(xz + hz_)));
      const float ng = tanhf(xn + rg * hn_);
      const float hprev = hT[pb][j];
      const float hnew = (1.f - zg) * ng + zg * hprev;
      h[(size_t)ab * H_ + j] = hnew;
      if (dir == 0) storeF(&houtF[((size_t)tf * B_ + ab) * rsF + j], hnew);
      else          storeF(&houtB[((size_t)tf * B_ + ab) * rsB + j], hnew);
      if (t == S_ - 1) outhid[((size_t)dir * B_ + ab) * H_ + j] = hnew;
    }
    __threadfence();   // release: drain h stores
    __syncthreads();
    if (tid == 0)
      __hip_atomic_fetch_add(hct, 1u, __ATOMIC_RELEASE, __HIP_MEMORY_SCOPE_AGENT);
  }
}

// --------------------------------- host side --------------------------------
static const size_t kCtrlBytes = 360704;
static const size_t kXpElems = (size_t)S_ * B_ * G3_;   // 100,663,296
static const size_t kHElems  = (size_t)S_ * B_ * H_;    //  33,554,432

struct Args {
  const int* src; const float* emb;
  const float *Wih_f, *Whh_f, *bih_f, *bhh_f, *gih_f, *beih_f, *ghh_f, *behh_f;
  const float *Wih_b, *Whh_b, *bih_b, *bhh_b, *gih_b, *beih_b, *ghh_b, *behh_b;
  const float *Wout, *bout;
  float* out; void* ws; hipStream_t stream;
};

// parallel: both directions' xp live (XT); h-histories alias into xp cols 0..511
template<typename XT>
static void run_parallel(const Args& a)
{
  float* hbuf = (float*)a.ws;
  float* part = hbuf + 65536;
  unsigned* statcnt = (unsigned*)(part + 24576);
  unsigned* hcnt = statcnt + 8;
  XT* xpf = (XT*)((char*)a.ws + kCtrlBytes);
  XT* xpb = xpf + kXpElems;
  float* outhid = a.out + kHElems;

  hipMemsetAsync(a.ws, 0, kCtrlBytes, a.stream);

  gemm_tile<XT,XT,0,0><<<dim3(512,12), dim3(256), 0, a.stream>>>(
      a.src, a.emb, (const XT*)nullptr, 0, (const XT*)nullptr, 0,
      a.Wih_f, xpf, nullptr, nullptr, G3_, E_);
  gemm_tile<XT,XT,0,0><<<dim3(512,12), dim3(256), 0, a.stream>>>(
      a.src, a.emb, (const XT*)nullptr, 0, (const XT*)nullptr, 0,
      a.Wih_b, xpb, nullptr, nullptr, G3_, E_);
  ln3_kernel<XT><<<dim3(S_*B_), dim3(256), 0, a.stream>>>(xpf, a.gih_f, a.beih_f, a.bih_f);
  ln3_kernel<XT><<<dim3(S_*B_), dim3(256), 0, a.stream>>>(xpb, a.gih_b, a.beih_b, a.bih_b);

  scan_kernel<XT,XT><<<dim3(256), dim3(256), 0, a.stream>>>(
      xpf, xpb, a.Whh_f, a.Whh_b, a.ghh_f, a.behh_f, a.bhh_f,
      a.ghh_b, a.behh_b, a.bhh_b, hbuf, part, statcnt, hcnt,
      xpf, G3_, xpb, G3_, outhid, 0);

  gemm_tile<XT,XT,1,1><<<dim3(512,4), dim3(256), 0, a.stream>>>(
      nullptr, nullptr, xpf, G3_, xpb, G3_,
      a.Wout, (XT*)nullptr, a.out, a.bout, H_, 2*H_);
}

// sequential: one xp buffer (XT) reused for both dirs; yf -> hf (HT),
// yb -> xp cols 0..511 (XT).
template<typename XT, typename HT>
static void run_sequential(const Args& a)
{
  float* hbuf = (float*)a.ws;
  float* part = hbuf + 65536;
  unsigned* statcnt = (unsigned*)(part + 24576);
  unsigned* hcnt = statcnt + 8;
  XT* xp = (XT*)((char*)a.ws + kCtrlBytes);
  HT* hf = (HT*)(xp + kXpElems);
  float* outhid = a.out + kHElems;

  hipMemsetAsync(a.ws, 0, kCtrlBytes, a.stream);

  gemm_tile<XT,XT,0,0><<<dim3(512,12), dim3(256), 0, a.stream>>>(
      a.src, a.emb, (const XT*)nullptr, 0, (const XT*)nullptr, 0,
      a.Wih_f, xp, nullptr, nullptr, G3_, E_);
  ln3_kernel<XT><<<dim3(S_*B_), dim3(256), 0, a.stream>>>(xp, a.gih_f, a.beih_f, a.bih_f);
  scan_kernel<XT,HT><<<dim3(128), dim3(256), 0, a.stream>>>(
      xp, xp, a.Whh_f, a.Whh_b, a.ghh_f, a.behh_f, a.bhh_f,
      a.ghh_b, a.behh_b, a.bhh_b, hbuf, part, statcnt, hcnt,
      hf, H_, xp, G3_, outhid, 0);

  gemm_tile<XT,XT,0,0><<<dim3(512,12), dim3(256), 0, a.stream>>>(
      a.src, a.emb, (const XT*)nullptr, 0, (const XT*)nullptr, 0,
      a.Wih_b, xp, nullptr, nullptr, G3_, E_);
  ln3_kernel<XT><<<dim3(S_*B_), dim3(256), 0, a.stream>>>(xp, a.gih_b, a.beih_b, a.bih_b);
  scan_kernel<XT,HT><<<dim3(128), dim3(256), 0, a.stream>>>(
      xp, xp, a.Whh_f, a.Whh_b, a.ghh_f, a.behh_f, a.bhh_f,
      a.ghh_b, a.behh_b, a.bhh_b, hbuf, part, statcnt, hcnt,
      hf, H_, xp, G3_, outhid, 1);

  gemm_tile<XT,HT,1,1><<<dim3(512,4), dim3(256), 0, a.stream>>>(
      nullptr, nullptr, hf, H_, xp, G3_,
      a.Wout, (XT*)nullptr, a.out, a.bout, H_, 2*H_);
}

extern "C" void kernel_launch(void* const* d_in, const int* in_sizes, int n_in,
                              void* d_out, int out_size, void* d_ws, size_t ws_size,
                              hipStream_t stream)
{
  Args a;
  a.src    = (const int*)  d_in[0];
  a.emb    = (const float*)d_in[1];
  a.Wih_f  = (const float*)d_in[2];
  a.Whh_f  = (const float*)d_in[3];
  a.bih_f  = (const float*)d_in[4];
  a.bhh_f  = (const float*)d_in[5];
  a.gih_f  = (const float*)d_in[6];
  a.beih_f = (const float*)d_in[7];
  a.ghh_f  = (const float*)d_in[8];
  a.behh_f = (const float*)d_in[9];
  a.Wih_b  = (const float*)d_in[10];
  a.Whh_b  = (const float*)d_in[11];
  a.bih_b  = (const float*)d_in[12];
  a.bhh_b  = (const float*)d_in[13];
  a.gih_b  = (const float*)d_in[14];
  a.beih_b = (const float*)d_in[15];
  a.ghh_b  = (const float*)d_in[16];
  a.behh_b = (const float*)d_in[17];
  a.Wout   = (const float*)d_in[18];
  a.bout   = (const float*)d_in[19];
  a.out = (float*)d_out;
  a.ws = d_ws;
  a.stream = stream;

  // tiers (ws < ~604MB known; fp32-parallel impossible)
  const size_t needA = kCtrlBytes + kXpElems*4 + kHElems*2;  // 470.1 MB fp32 xp, bf16 hf
  const size_t needB = kCtrlBytes + 2*kXpElems*2;            // 403.0 MB bf16 parallel
  const size_t needC = kCtrlBytes + kXpElems*2 + kHElems*4;  // 335.9 MB bf16 xp, fp32 hf
  const size_t needD = kCtrlBytes + kXpElems*2 + kHElems*2;  // 268.8 MB bf16 all

  const bool sane = (n_in == 20) && (in_sizes[0] == S_*B_) && (in_sizes[1] == 32000*E_)
                 && (in_sizes[3] == G3_*H_) && (in_sizes[18] == H_*2*H_);

  float sigv = 0.f;
  bool ran = false;
  if (!sane) {
    sigv = 20000.f + (float)n_in;
  } else if (ws_size >= needA) { run_sequential<float, bf16>(a); ran = true; }
  else if (ws_size >= needB) { run_parallel<bf16>(a);            ran = true; }
  else if (ws_size >= needC) { run_sequential<bf16, float>(a);   ran = true; }
  else if (ws_size >= needD) { run_sequential<bf16, bf16>(a);    ran = true; }
  else {
    unsigned wsMB = (unsigned)(ws_size >> 20);
    if (wsMB > 998) wsMB = 998;
    sigv = 1000.f + (float)wsMB;
  }

  if (!ran) {
    signal_kernel<<<dim3(1024), dim3(256), 0, stream>>>(a.out, (long)out_size, sigv);
  } else {
    hipError_t e = hipGetLastError();
    if (e != hipSuccess) {
      signal_kernel<<<dim3(1024), dim3(256), 0, stream>>>(a.out, (long)out_size,
                                                          10000.f + (float)(int)e);
    }
  }
}

// Round 5
// 54994.214 us; speedup vs baseline: 2.0574x; 2.0574x over previous
//
#include <hip/hip_runtime.h>
#include <hip/hip_bf16.h>

#define S_ 1024
#define B_ 64
#define E_ 512
#define H_ 512
#define G3_ 1536

typedef __hip_bfloat16 bf16;
typedef unsigned long long ULL;

// ---------- dtype helpers ----------
template<typename T> struct alignas(4*sizeof(T)) V4 { T v[4]; };

__device__ __forceinline__ float toF(float x){ return x; }
__device__ __forceinline__ float toF(bf16 x){ return __bfloat162float(x); }
__device__ __forceinline__ void storeF(float* p, float v){ *p = v; }
__device__ __forceinline__ void storeF(bf16* p, float v){ *p = __float2bfloat16(v); }

__device__ __forceinline__ ULL cohLoad8(const ULL* p){
  return __hip_atomic_load(p, __ATOMIC_RELAXED, __HIP_MEMORY_SCOPE_AGENT);
}
__device__ __forceinline__ void cohStore4(float* p, float v){
  __hip_atomic_store(p, v, __ATOMIC_RELAXED, __HIP_MEMORY_SCOPE_AGENT);
}

// ------------------------------ signal kernel -------------------------------
__global__ __launch_bounds__(256)
void signal_kernel(float* __restrict__ out, long n, float v)
{
  long i = (long)blockIdx.x * 256 + threadIdx.x;
  const long stride = (long)gridDim.x * 256;
  for (; i < n; i += stride) out[i] = v;
}

// ------------------------------- tiled GEMM ---------------------------------
// C[m][n] = sum_k A[m][k] * W[n][k]
// AMODE 0: A[m][k] = emb[src[m]][k] * (src[m]!=0)            (fp32 gather)
// AMODE 1: A[m][k] = k<H ? Af[m*rsF+k] (HT) : Ab[m*rsB+k-H] (XT)
// EPI 0: store raw XT to Cx (row stride N). EPI 1: store f32 tanh(acc+bias).
template<typename XT, typename HT, int AMODE, int EPI>
__global__ __launch_bounds__(256, 2)
void gemm_tile(const int* __restrict__ src, const float* __restrict__ emb,
               const HT* __restrict__ Af, int rsF, const XT* __restrict__ Ab, int rsB,
               const float* __restrict__ W,
               XT* __restrict__ Cx, float* __restrict__ Cf, const float* __restrict__ bias,
               int N, int K)
{
  __shared__ float As[16][132];
  __shared__ float Bs[16][132];
  __shared__ int s_tok[128];
  const int m0 = blockIdx.x * 128;
  const int n0 = blockIdx.y * 128;
  const int tid = threadIdx.x;
  const int tx = tid & 15, ty = tid >> 4;

  if constexpr (AMODE == 0) {
    if (tid < 128) s_tok[tid] = src[m0 + tid];
  }
  __syncthreads();

  float acc[8][8];
  #pragma unroll
  for (int i = 0; i < 8; ++i)
    #pragma unroll
    for (int j = 0; j < 8; ++j) acc[i][j] = 0.f;

  for (int k0 = 0; k0 < K; k0 += 16) {
    #pragma unroll
    for (int i = 0; i < 2; ++i) {
      const int f = tid * 2 + i;
      const int r = f >> 2, kq = f & 3;
      const int kk = k0 + kq * 4;
      float a0, a1, a2, a3;
      if constexpr (AMODE == 0) {
        const int tok = s_tok[r];
        if (tok != 0) {
          float4 v = *(const float4*)(emb + (size_t)tok * E_ + kk);
          a0 = v.x; a1 = v.y; a2 = v.z; a3 = v.w;
        } else { a0 = a1 = a2 = a3 = 0.f; }
      } else {
        if (kk < H_) {
          V4<HT> v = *(const V4<HT>*)(Af + (size_t)(m0 + r) * rsF + kk);
          a0 = toF(v.v[0]); a1 = toF(v.v[1]); a2 = toF(v.v[2]); a3 = toF(v.v[3]);
        } else {
          V4<XT> v = *(const V4<XT>*)(Ab + (size_t)(m0 + r) * rsB + (kk - H_));
          a0 = toF(v.v[0]); a1 = toF(v.v[1]); a2 = toF(v.v[2]); a3 = toF(v.v[3]);
        }
      }
      As[kq*4+0][r] = a0; As[kq*4+1][r] = a1; As[kq*4+2][r] = a2; As[kq*4+3][r] = a3;
      float4 b = *(const float4*)(W + (size_t)(n0 + r) * K + kk);
      Bs[kq*4+0][r] = b.x; Bs[kq*4+1][r] = b.y; Bs[kq*4+2][r] = b.z; Bs[kq*4+3][r] = b.w;
    }
    __syncthreads();
    #pragma unroll
    for (int k = 0; k < 16; ++k) {
      float4 ra0 = *(const float4*)&As[k][ty*8];
      float4 ra1 = *(const float4*)&As[k][ty*8+4];
      float4 rb0 = *(const float4*)&Bs[k][tx*8];
      float4 rb1 = *(const float4*)&Bs[k][tx*8+4];
      float fa[8] = {ra0.x,ra0.y,ra0.z,ra0.w,ra1.x,ra1.y,ra1.z,ra1.w};
      float fb[8] = {rb0.x,rb0.y,rb0.z,rb0.w,rb1.x,rb1.y,rb1.z,rb1.w};
      #pragma unroll
      for (int i = 0; i < 8; ++i)
        #pragma unroll
        for (int j = 0; j < 8; ++j) acc[i][j] += fa[i] * fb[j];
    }
    __syncthreads();
  }

  if constexpr (EPI == 0) {
    #pragma unroll
    for (int i = 0; i < 8; ++i) {
      XT* crow = Cx + (size_t)(m0 + ty*8 + i) * N + n0 + tx*8;
      V4<XT> o0, o1;
      #pragma unroll
      for (int c = 0; c < 4; ++c) { storeF(&o0.v[c], acc[i][c]); storeF(&o1.v[c], acc[i][4+c]); }
      ((V4<XT>*)crow)[0] = o0; ((V4<XT>*)crow)[1] = o1;
    }
  } else {
    float bj[8];
    #pragma unroll
    for (int j = 0; j < 8; ++j) bj[j] = bias[n0 + tx*8 + j];
    #pragma unroll
    for (int i = 0; i < 8; ++i) {
      float* crow = Cf + (size_t)(m0 + ty*8 + i) * N + n0 + tx*8;
      float4 o0, o1;
      o0.x = tanhf(acc[i][0]+bj[0]); o0.y = tanhf(acc[i][1]+bj[1]);
      o0.z = tanhf(acc[i][2]+bj[2]); o0.w = tanhf(acc[i][3]+bj[3]);
      o1.x = tanhf(acc[i][4]+bj[4]); o1.y = tanhf(acc[i][5]+bj[5]);
      o1.z = tanhf(acc[i][6]+bj[6]); o1.w = tanhf(acc[i][7]+bj[7]);
      ((float4*)crow)[0] = o0; ((float4*)crow)[1] = o1;
    }
  }
}

// -------- in-place LayerNorm per 512-chunk (3 gates) + gain/bias fold -------
template<typename XT>
__global__ __launch_bounds__(256)
void ln3_kernel(XT* __restrict__ xp, const float* __restrict__ g,
                const float* __restrict__ be, const float* __restrict__ b)
{
  const size_t base = (size_t)blockIdx.x * G3_;
  const int t = threadIdx.x;
  float v[6];
  #pragma unroll
  for (int gg = 0; gg < 3; ++gg) {
    v[gg*2+0] = toF(xp[base + gg*512 + t]);
    v[gg*2+1] = toF(xp[base + gg*512 + 256 + t]);
  }
  float s0 = v[0]+v[1], q0 = v[0]*v[0]+v[1]*v[1];
  float s1 = v[2]+v[3], q1 = v[2]*v[2]+v[3]*v[3];
  float s2 = v[4]+v[5], q2 = v[4]*v[4]+v[5]*v[5];
  #pragma unroll
  for (int m = 1; m < 64; m <<= 1) {
    s0 += __shfl_xor(s0, m); q0 += __shfl_xor(q0, m);
    s1 += __shfl_xor(s1, m); q1 += __shfl_xor(q1, m);
    s2 += __shfl_xor(s2, m); q2 += __shfl_xor(q2, m);
  }
  __shared__ float red[4][6];
  __shared__ float stat[6];
  const int wid = t >> 6, lane = t & 63;
  if (lane == 0) { red[wid][0]=s0; red[wid][1]=q0; red[wid][2]=s1; red[wid][3]=q1; red[wid][4]=s2; red[wid][5]=q2; }
  __syncthreads();
  if (t < 6) stat[t] = red[0][t] + red[1][t] + red[2][t] + red[3][t];
  __syncthreads();
  #pragma unroll
  for (int gg = 0; gg < 3; ++gg) {
    const float mu  = stat[gg*2]   * (1.f/512.f);
    const float var = stat[gg*2+1] * (1.f/512.f) - mu*mu;
    const float sc  = rsqrtf(var + 1e-5f);
    #pragma unroll
    for (int u = 0; u < 2; ++u) {
      const int c = gg*512 + u*256 + t;
      storeF(&xp[base + c], (v[gg*2+u] - mu) * sc * g[c] + be[c] + b[c]);
    }
  }
}

// --------------------------- persistent scan kernel -------------------------
// Geometry: group = 8 batches; 8 groups per direction; 32 j-slice blocks per
// group. Sequential launch: grid 256 (one dir). Parallel: grid 512 (both).
// ALL cross-block data moves through L3 via relaxed agent-scope atomics
// (sc-flagged, bypass L1/L2 -> cross-XCD coherent). NO acquire/release cache
// flushes anywhere in the loop. Ordering: s_waitcnt vmcnt(0) + __syncthreads
// before counter bump; reads issued only after counter observed.
template<typename XT, typename HT>
__global__ __launch_bounds__(256, 2)
void scan_kernel(const XT* __restrict__ xp_f, const XT* __restrict__ xp_b,
                 const float* __restrict__ Whh_f, const float* __restrict__ Whh_b,
                 const float* __restrict__ gf, const float* __restrict__ bef, const float* __restrict__ bfv,
                 const float* __restrict__ gbv, const float* __restrict__ beb, const float* __restrict__ bbv,
                 float* __restrict__ hbuf, float* __restrict__ part,
                 unsigned* __restrict__ statcnt, unsigned* __restrict__ hcnt,
                 HT* __restrict__ houtF, int rsF, XT* __restrict__ houtB, int rsB,
                 float* __restrict__ outhid, int dirbase)
{
  __shared__ float hT[8][512];       // 16 KB staged h for this batch-group
  __shared__ float red[4][16][26];   // cross-wave k-slice reduction
  __shared__ float statL[48];        // [b8][gate3][sum,sumsq]

  const int bid  = blockIdx.x;
  const int gidx = dirbase*8 + (bid >> 5);   // global group 0..15
  const int dir  = gidx >> 3;
  const int bg   = gidx & 7;                 // batch group (8 batches)
  const int js   = bid & 31;                 // j slice
  const int tid  = threadIdx.x;
  const int jloc = tid & 15;
  const int pb   = tid >> 4;                 // dots: k-slice id; gates: b id
  const int wid  = tid >> 6;
  const int ksw  = (tid >> 4) & 3;
  const int j    = js*16 + jloc;

  const XT* xp   = dir ? xp_b : xp_f;
  const float* W = dir ? Whh_b : Whh_f;
  const float* gv  = dir ? gbv : gf;
  const float* bev = dir ? beb : bef;
  const float* bv  = dir ? bbv : bfv;
  float* h = hbuf + dir * (B_ * H_);
  float* pgrp = part + (size_t)gidx * (48*32);
  unsigned* scnt = statcnt + gidx;
  unsigned* hct  = hcnt    + gidx;

  // W slice in registers; chunk order permuted by ksw (bank-conflict spread)
  float w[3][32];
  {
    #pragma unroll
    for (int r = 0; r < 3; ++r) {
      const float* wr = W + (size_t)(r*H_ + j) * H_ + pb * 32;
      #pragma unroll
      for (int c = 0; c < 8; ++c) {
        const int p = (c + ksw*2) & 7;
        float4 f = *(const float4*)(wr + p*4);
        w[r][c*4+0] = f.x; w[r][c*4+1] = f.y; w[r][c*4+2] = f.z; w[r][c*4+3] = f.w;
      }
    }
  }
  const float gr0 = gv[j],            gr1 = gv[H_+j],               gr2 = gv[2*H_+j];
  const float gb0 = bev[j] + bv[j],   gb1 = bev[H_+j] + bv[H_+j],   gb2 = bev[2*H_+j] + bv[2*H_+j];

  int dead = 0;

  for (int t = 0; t < S_; ++t) {
    // ---- barrier 1: h(t) complete (32 bumps per step per group) ----
    if (tid == 0 && !dead) {
      const unsigned tgt = 32u * (unsigned)t;
      int guard = 0;
      while (__hip_atomic_load(hct, __ATOMIC_RELAXED, __HIP_MEMORY_SCOPE_AGENT) < tgt) {
        __builtin_amdgcn_s_sleep(1);
        if (++guard > (1 << 22)) { dead = 1; break; }
      }
    }
    __syncthreads();

    // stage h tile (8 b x 512 f32) via coherent 8B loads -> LDS
    {
      const int row = tid >> 5;          // 0..7
      const int seg = tid & 31;          // 32 threads per row, 8 ULL each
      const ULL* hr = (const ULL*)(h + (size_t)(bg*8 + row) * H_) + seg*8;
      ULL v[8];
      #pragma unroll
      for (int i = 0; i < 8; ++i) v[i] = cohLoad8(hr + i);
      ULL* dst = (ULL*)&hT[row][0] + seg*8;
      #pragma unroll
      for (int i = 0; i < 8; ++i) dst[i] = v[i];
    }
    __syncthreads();

    // k-sliced dots for the 8 b of this group
    for (int b = 0; b < 8; ++b) {
      float a0 = 0.f, a1 = 0.f, a2 = 0.f;
      #pragma unroll
      for (int c = 0; c < 8; ++c) {
        const int p = (c + ksw*2) & 7;
        const float4 hv = *(const float4*)&hT[b][pb*32 + p*4];
        a0 += hv.x*w[0][c*4+0] + hv.y*w[0][c*4+1] + hv.z*w[0][c*4+2] + hv.w*w[0][c*4+3];
        a1 += hv.x*w[1][c*4+0] + hv.y*w[1][c*4+1] + hv.z*w[1][c*4+2] + hv.w*w[1][c*4+3];
        a2 += hv.x*w[2][c*4+0] + hv.y*w[2][c*4+1] + hv.z*w[2][c*4+2] + hv.w*w[2][c*4+3];
      }
      a0 += __shfl_xor(a0, 16); a0 += __shfl_xor(a0, 32);
      a1 += __shfl_xor(a1, 16); a1 += __shfl_xor(a1, 32);
      a2 += __shfl_xor(a2, 16); a2 += __shfl_xor(a2, 32);
      if (ksw == 0) {
        red[wid][jloc][b*3+0] = a0; red[wid][jloc][b*3+1] = a1; red[wid][jloc][b*3+2] = a2;
      }
    }
    __syncthreads();

    float vr = 0.f, vz = 0.f, vn = 0.f;
    if (pb < 8) {
      vr = red[0][jloc][pb*3+0]+red[1][jloc][pb*3+0]+red[2][jloc][pb*3+0]+red[3][jloc][pb*3+0];
      vz = red[0][jloc][pb*3+1]+red[1][jloc][pb*3+1]+red[2][jloc][pb*3+1]+red[3][jloc][pb*3+1];
      vn = red[0][jloc][pb*3+2]+red[1][jloc][pb*3+2]+red[2][jloc][pb*3+2]+red[3][jloc][pb*3+2];

      // LN-stat partials over this block's 16 j -> group buffer [48][32]
      float sr = vr, qr = vr*vr, sz = vz, qz = vz*vz, sn = vn, qn = vn*vn;
      #pragma unroll
      for (int m = 1; m < 16; m <<= 1) {
        sr += __shfl_xor(sr, m); qr += __shfl_xor(qr, m);
        sz += __shfl_xor(sz, m); qz += __shfl_xor(qz, m);
        sn += __shfl_xor(sn, m); qn += __shfl_xor(qn, m);
      }
      if (jloc == 0) {
        cohStore4(&pgrp[(pb*6+0)*32 + js], sr);
        cohStore4(&pgrp[(pb*6+1)*32 + js], qr);
        cohStore4(&pgrp[(pb*6+2)*32 + js], sz);
        cohStore4(&pgrp[(pb*6+3)*32 + js], qz);
        cohStore4(&pgrp[(pb*6+4)*32 + js], sn);
        cohStore4(&pgrp[(pb*6+5)*32 + js], qn);
      }
    }
    asm volatile("s_waitcnt vmcnt(0)" ::: "memory");
    __syncthreads();

    // ---- barrier 2: all 32 blocks' partials at L3 ----
    if (tid == 0) {
      __hip_atomic_fetch_add(scnt, 1u, __ATOMIC_RELAXED, __HIP_MEMORY_SCOPE_AGENT);
      if (!dead) {
        const unsigned tgt = 32u * (unsigned)(t + 1);
        int guard = 0;
        while (__hip_atomic_load(scnt, __ATOMIC_RELAXED, __HIP_MEMORY_SCOPE_AGENT) < tgt) {
          __builtin_amdgcn_s_sleep(1);
          if (++guard > (1 << 22)) { dead = 1; break; }
        }
      }
    }
    __syncthreads();

    // reduce 32 slot-partials -> LN stats (8 b x 3 gates x {sum, sumsq})
    if (tid < 48) {
      const ULL* prow = (const ULL*)(pgrp + tid * 32);
      float s = 0.f;
      #pragma unroll
      for (int u = 0; u < 16; ++u) {
        ULL v = cohLoad8(prow + u);
        union { ULL u64; float f[2]; } cv; cv.u64 = v;
        s += cv.f[0] + cv.f[1];
      }
      statL[tid] = s;
    }
    __syncthreads();

    // gates + h update (thread owns (b=pb<8, j))
    if (pb < 8) {
      const int ab = bg*8 + pb;
      const float mur   = statL[pb*6+0]*(1.f/512.f);
      const float var_r = statL[pb*6+1]*(1.f/512.f) - mur*mur;
      const float muz   = statL[pb*6+2]*(1.f/512.f);
      const float var_z = statL[pb*6+3]*(1.f/512.f) - muz*muz;
      const float mun   = statL[pb*6+4]*(1.f/512.f);
      const float var_n = statL[pb*6+5]*(1.f/512.f) - mun*mun;
      const float hr_ = (vr - mur) * rsqrtf(var_r + 1e-5f) * gr0 + gb0;
      const float hz_ = (vz - muz) * rsqrtf(var_z + 1e-5f) * gr1 + gb1;
      const float hn_ = (vn - mun) * rsqrtf(var_n + 1e-5f) * gr2 + gb2;
      const int tf = dir ? (S_ - 1 - t) : t;
      const size_t xbase = ((size_t)tf * B_ + ab) * G3_;
      const float xr = toF(xp[xbase + j]);
      const float xz = toF(xp[xbase + H_ + j]);
      const float xn = toF(xp[xbase + 2*H_ + j]);
      const float rg = 1.f / (1.f + __expf(-(xr + hr_)));
      const float zg = 1.f / (1.f + __expf(-(xz + hz_)));
      const float ng = tanhf(xn + rg * hn_);
      const float hprev = hT[pb][j];
      const float hnew = (1.f - zg) * ng + zg * hprev;
      cohStore4(&h[(size_t)ab * H_ + j], hnew);
      if (dir == 0) storeF(&houtF[((size_t)tf * B_ + ab) * rsF + j], hnew);
      else          storeF(&houtB[((size_t)tf * B_ + ab) * rsB + j], hnew);
      if (t == S_ - 1) outhid[((size_t)dir * B_ + ab) * H_ + j] = hnew;
    }
    asm volatile("s_waitcnt vmcnt(0)" ::: "memory");
    __syncthreads();
    if (tid == 0)
      __hip_atomic_fetch_add(hct, 1u, __ATOMIC_RELAXED, __HIP_MEMORY_SCOPE_AGENT);
  }
}

// --------------------------------- host side --------------------------------
static const size_t kCtrlBytes = 360704;  // hbuf 256K + part 96K + counters
static const size_t kXpElems = (size_t)S_ * B_ * G3_;   // 100,663,296
static const size_t kHElems  = (size_t)S_ * B_ * H_;    //  33,554,432

struct Args {
  const int* src; const float* emb;
  const float *Wih_f, *Whh_f, *bih_f, *bhh_f, *gih_f, *beih_f, *ghh_f, *behh_f;
  const float *Wih_b, *Whh_b, *bih_b, *bhh_b, *gih_b, *beih_b, *ghh_b, *behh_b;
  const float *Wout, *bout;
  float* out; void* ws; hipStream_t stream;
};

// parallel: both directions' xp live (XT); h-histories alias into xp cols 0..511
template<typename XT>
static void run_parallel(const Args& a)
{
  float* hbuf = (float*)a.ws;
  float* part = hbuf + 65536;
  unsigned* statcnt = (unsigned*)(part + 24576);
  unsigned* hcnt = statcnt + 16;
  XT* xpf = (XT*)((char*)a.ws + kCtrlBytes);
  XT* xpb = xpf + kXpElems;
  float* outhid = a.out + kHElems;

  hipMemsetAsync(a.ws, 0, kCtrlBytes, a.stream);

  gemm_tile<XT,XT,0,0><<<dim3(512,12), dim3(256), 0, a.stream>>>(
      a.src, a.emb, (const XT*)nullptr, 0, (const XT*)nullptr, 0,
      a.Wih_f, xpf, nullptr, nullptr, G3_, E_);
  gemm_tile<XT,XT,0,0><<<dim3(512,12), dim3(256), 0, a.stream>>>(
      a.src, a.emb, (const XT*)nullptr, 0, (const XT*)nullptr, 0,
      a.Wih_b, xpb, nullptr, nullptr, G3_, E_);
  ln3_kernel<XT><<<dim3(S_*B_), dim3(256), 0, a.stream>>>(xpf, a.gih_f, a.beih_f, a.bih_f);
  ln3_kernel<XT><<<dim3(S_*B_), dim3(256), 0, a.stream>>>(xpb, a.gih_b, a.beih_b, a.bih_b);

  scan_kernel<XT,XT><<<dim3(512), dim3(256), 0, a.stream>>>(
      xpf, xpb, a.Whh_f, a.Whh_b, a.ghh_f, a.behh_f, a.bhh_f,
      a.ghh_b, a.behh_b, a.bhh_b, hbuf, part, statcnt, hcnt,
      xpf, G3_, xpb, G3_, outhid, 0);

  gemm_tile<XT,XT,1,1><<<dim3(512,4), dim3(256), 0, a.stream>>>(
      nullptr, nullptr, xpf, G3_, xpb, G3_,
      a.Wout, (XT*)nullptr, a.out, a.bout, H_, 2*H_);
}

// sequential: one xp buffer (XT) reused; yf -> hf (HT), yb -> xp cols 0..511
template<typename XT, typename HT>
static void run_sequential(const Args& a)
{
  float* hbuf = (float*)a.ws;
  float* part = hbuf + 65536;
  unsigned* statcnt = (unsigned*)(part + 24576);
  unsigned* hcnt = statcnt + 16;
  XT* xp = (XT*)((char*)a.ws + kCtrlBytes);
  HT* hf = (HT*)(xp + kXpElems);
  float* outhid = a.out + kHElems;

  hipMemsetAsync(a.ws, 0, kCtrlBytes, a.stream);

  gemm_tile<XT,XT,0,0><<<dim3(512,12), dim3(256), 0, a.stream>>>(
      a.src, a.emb, (const XT*)nullptr, 0, (const XT*)nullptr, 0,
      a.Wih_f, xp, nullptr, nullptr, G3_, E_);
  ln3_kernel<XT><<<dim3(S_*B_), dim3(256), 0, a.stream>>>(xp, a.gih_f, a.beih_f, a.bih_f);
  scan_kernel<XT,HT><<<dim3(256), dim3(256), 0, a.stream>>>(
      xp, xp, a.Whh_f, a.Whh_b, a.ghh_f, a.behh_f, a.bhh_f,
      a.ghh_b, a.behh_b, a.bhh_b, hbuf, part, statcnt, hcnt,
      hf, H_, xp, G3_, outhid, 0);

  gemm_tile<XT,XT,0,0><<<dim3(512,12), dim3(256), 0, a.stream>>>(
      a.src, a.emb, (const XT*)nullptr, 0, (const XT*)nullptr, 0,
      a.Wih_b, xp, nullptr, nullptr, G3_, E_);
  ln3_kernel<XT><<<dim3(S_*B_), dim3(256), 0, a.stream>>>(xp, a.gih_b, a.beih_b, a.bih_b);
  scan_kernel<XT,HT><<<dim3(256), dim3(256), 0, a.stream>>>(
      xp, xp, a.Whh_f, a.Whh_b, a.ghh_f, a.behh_f, a.bhh_f,
      a.ghh_b, a.behh_b, a.bhh_b, hbuf, part, statcnt, hcnt,
      hf, H_, xp, G3_, outhid, 1);

  gemm_tile<XT,HT,1,1><<<dim3(512,4), dim3(256), 0, a.stream>>>(
      nullptr, nullptr, hf, H_, xp, G3_,
      a.Wout, (XT*)nullptr, a.out, a.bout, H_, 2*H_);
}

extern "C" void kernel_launch(void* const* d_in, const int* in_sizes, int n_in,
                              void* d_out, int out_size, void* d_ws, size_t ws_size,
                              hipStream_t stream)
{
  Args a;
  a.src    = (const int*)  d_in[0];
  a.emb    = (const float*)d_in[1];
  a.Wih_f  = (const float*)d_in[2];
  a.Whh_f  = (const float*)d_in[3];
  a.bih_f  = (const float*)d_in[4];
  a.bhh_f  = (const float*)d_in[5];
  a.gih_f  = (const float*)d_in[6];
  a.beih_f = (const float*)d_in[7];
  a.ghh_f  = (const float*)d_in[8];
  a.behh_f = (const float*)d_in[9];
  a.Wih_b  = (const float*)d_in[10];
  a.Whh_b  = (const float*)d_in[11];
  a.bih_b  = (const float*)d_in[12];
  a.bhh_b  = (const float*)d_in[13];
  a.gih_b  = (const float*)d_in[14];
  a.beih_b = (const float*)d_in[15];
  a.ghh_b  = (const float*)d_in[16];
  a.behh_b = (const float*)d_in[17];
  a.Wout   = (const float*)d_in[18];
  a.bout   = (const float*)d_in[19];
  a.out = (float*)d_out;
  a.ws = d_ws;
  a.stream = stream;

  int dev = 0, cus = 0;
  hipGetDevice(&dev);
  hipDeviceGetAttribute(&cus, hipDeviceAttributeMultiprocessorCount, dev);

  const size_t needA = kCtrlBytes + kXpElems*4 + kHElems*2;  // 470.1 MB fp32 xp, bf16 hf
  const size_t needB = kCtrlBytes + 2*kXpElems*2;            // 403.0 MB bf16 parallel
  const size_t needC = kCtrlBytes + kXpElems*2 + kHElems*4;  // 335.9 MB bf16 xp, fp32 hf
  const size_t needD = kCtrlBytes + kXpElems*2 + kHElems*2;  // 268.8 MB bf16 all

  const bool sane = (n_in == 20) && (in_sizes[0] == S_*B_) && (in_sizes[1] == 32000*E_)
                 && (in_sizes[3] == G3_*H_) && (in_sizes[18] == H_*2*H_);

  float sigv = 0.f;
  bool ran = false;
  if (!sane) {
    sigv = 20000.f + (float)n_in;
  } else if (cus < 256) {
    sigv = 100000.f + (float)cus;
  } else if (ws_size >= needA) { run_sequential<float, bf16>(a); ran = true; }
  else if (ws_size >= needB) { run_parallel<bf16>(a);            ran = true; }
  else if (ws_size >= needC) { run_sequential<bf16, float>(a);   ran = true; }
  else if (ws_size >= needD) { run_sequential<bf16, bf16>(a);    ran = true; }
  else {
    unsigned wsMB = (unsigned)(ws_size >> 20);
    if (wsMB > 998) wsMB = 998;
    sigv = 1000.f + (float)wsMB;
  }

  if (!ran) {
    signal_kernel<<<dim3(1024), dim3(256), 0, stream>>>(a.out, (long)out_size, sigv);
  } else {
    hipError_t e = hipGetLastError();
    if (e != hipSuccess) {
      signal_kernel<<<dim3(1024), dim3(256), 0, stream>>>(a.out, (long)out_size,
                                                          10000.f + (float)(int)e);
    }
  }
}

// Round 6
// 20596.033 us; speedup vs baseline: 5.4935x; 2.6701x over previous
//
#include <hip/hip_runtime.h>
#include <hip/hip_bf16.h>

#define S_ 1024
#define B_ 64
#define E_ 512
#define H_ 512
#define G3_ 1536

typedef __hip_bfloat16 bf16;
typedef unsigned long long ULL;

// ---------- dtype helpers ----------
template<typename T> struct alignas(4*sizeof(T)) V4 { T v[4]; };

__device__ __forceinline__ float toF(float x){ return x; }
__device__ __forceinline__ float toF(bf16 x){ return __bfloat162float(x); }
__device__ __forceinline__ void storeF(float* p, float v){ *p = v; }
__device__ __forceinline__ void storeF(bf16* p, float v){ *p = __float2bfloat16(v); }

__device__ __forceinline__ ULL cohLoad8(const ULL* p){
  return __hip_atomic_load(p, __ATOMIC_RELAXED, __HIP_MEMORY_SCOPE_AGENT);
}
__device__ __forceinline__ void cohStore4(float* p, float v){
  __hip_atomic_store(p, v, __ATOMIC_RELAXED, __HIP_MEMORY_SCOPE_AGENT);
}
__device__ __forceinline__ unsigned flagLoad(const unsigned* p){
  return __hip_atomic_load(p, __ATOMIC_RELAXED, __HIP_MEMORY_SCOPE_AGENT);
}
__device__ __forceinline__ void flagStore(unsigned* p, unsigned v){
  __hip_atomic_store(p, v, __ATOMIC_RELAXED, __HIP_MEMORY_SCOPE_AGENT);
}

// ------------------------------ signal kernel -------------------------------
__global__ __launch_bounds__(256)
void signal_kernel(float* __restrict__ out, long n, float v)
{
  long i = (long)blockIdx.x * 256 + threadIdx.x;
  const long stride = (long)gridDim.x * 256;
  for (; i < n; i += stride) out[i] = v;
}

// ------------------------------- tiled GEMM ---------------------------------
// C[m][n] = sum_k A[m][k] * W[n][k]
// AMODE 0: A[m][k] = emb[src[m]][k] * (src[m]!=0)            (fp32 gather)
// AMODE 1: A[m][k] = k<H ? Af[m*rsF+k] (HT) : Ab[m*rsB+k-H] (XT)
// EPI 0: store raw XT to Cx (row stride N). EPI 1: store f32 tanh(acc+bias).
template<typename XT, typename HT, int AMODE, int EPI>
__global__ __launch_bounds__(256, 2)
void gemm_tile(const int* __restrict__ src, const float* __restrict__ emb,
               const HT* __restrict__ Af, int rsF, const XT* __restrict__ Ab, int rsB,
               const float* __restrict__ W,
               XT* __restrict__ Cx, float* __restrict__ Cf, const float* __restrict__ bias,
               int N, int K)
{
  __shared__ float As[16][132];
  __shared__ float Bs[16][132];
  __shared__ int s_tok[128];
  const int m0 = blockIdx.x * 128;
  const int n0 = blockIdx.y * 128;
  const int tid = threadIdx.x;
  const int tx = tid & 15, ty = tid >> 4;

  if constexpr (AMODE == 0) {
    if (tid < 128) s_tok[tid] = src[m0 + tid];
  }
  __syncthreads();

  float acc[8][8];
  #pragma unroll
  for (int i = 0; i < 8; ++i)
    #pragma unroll
    for (int j = 0; j < 8; ++j) acc[i][j] = 0.f;

  for (int k0 = 0; k0 < K; k0 += 16) {
    #pragma unroll
    for (int i = 0; i < 2; ++i) {
      const int f = tid * 2 + i;
      const int r = f >> 2, kq = f & 3;
      const int kk = k0 + kq * 4;
      float a0, a1, a2, a3;
      if constexpr (AMODE == 0) {
        const int tok = s_tok[r];
        if (tok != 0) {
          float4 v = *(const float4*)(emb + (size_t)tok * E_ + kk);
          a0 = v.x; a1 = v.y; a2 = v.z; a3 = v.w;
        } else { a0 = a1 = a2 = a3 = 0.f; }
      } else {
        if (kk < H_) {
          V4<HT> v = *(const V4<HT>*)(Af + (size_t)(m0 + r) * rsF + kk);
          a0 = toF(v.v[0]); a1 = toF(v.v[1]); a2 = toF(v.v[2]); a3 = toF(v.v[3]);
        } else {
          V4<XT> v = *(const V4<XT>*)(Ab + (size_t)(m0 + r) * rsB + (kk - H_));
          a0 = toF(v.v[0]); a1 = toF(v.v[1]); a2 = toF(v.v[2]); a3 = toF(v.v[3]);
        }
      }
      As[kq*4+0][r] = a0; As[kq*4+1][r] = a1; As[kq*4+2][r] = a2; As[kq*4+3][r] = a3;
      float4 b = *(const float4*)(W + (size_t)(n0 + r) * K + kk);
      Bs[kq*4+0][r] = b.x; Bs[kq*4+1][r] = b.y; Bs[kq*4+2][r] = b.z; Bs[kq*4+3][r] = b.w;
    }
    __syncthreads();
    #pragma unroll
    for (int k = 0; k < 16; ++k) {
      float4 ra0 = *(const float4*)&As[k][ty*8];
      float4 ra1 = *(const float4*)&As[k][ty*8+4];
      float4 rb0 = *(const float4*)&Bs[k][tx*8];
      float4 rb1 = *(const float4*)&Bs[k][tx*8+4];
      float fa[8] = {ra0.x,ra0.y,ra0.z,ra0.w,ra1.x,ra1.y,ra1.z,ra1.w};
      float fb[8] = {rb0.x,rb0.y,rb0.z,rb0.w,rb1.x,rb1.y,rb1.z,rb1.w};
      #pragma unroll
      for (int i = 0; i < 8; ++i)
        #pragma unroll
        for (int j = 0; j < 8; ++j) acc[i][j] += fa[i] * fb[j];
    }
    __syncthreads();
  }

  if constexpr (EPI == 0) {
    #pragma unroll
    for (int i = 0; i < 8; ++i) {
      XT* crow = Cx + (size_t)(m0 + ty*8 + i) * N + n0 + tx*8;
      V4<XT> o0, o1;
      #pragma unroll
      for (int c = 0; c < 4; ++c) { storeF(&o0.v[c], acc[i][c]); storeF(&o1.v[c], acc[i][4+c]); }
      ((V4<XT>*)crow)[0] = o0; ((V4<XT>*)crow)[1] = o1;
    }
  } else {
    float bj[8];
    #pragma unroll
    for (int j = 0; j < 8; ++j) bj[j] = bias[n0 + tx*8 + j];
    #pragma unroll
    for (int i = 0; i < 8; ++i) {
      float* crow = Cf + (size_t)(m0 + ty*8 + i) * N + n0 + tx*8;
      float4 o0, o1;
      o0.x = tanhf(acc[i][0]+bj[0]); o0.y = tanhf(acc[i][1]+bj[1]);
      o0.z = tanhf(acc[i][2]+bj[2]); o0.w = tanhf(acc[i][3]+bj[3]);
      o1.x = tanhf(acc[i][4]+bj[4]); o1.y = tanhf(acc[i][5]+bj[5]);
      o1.z = tanhf(acc[i][6]+bj[6]); o1.w = tanhf(acc[i][7]+bj[7]);
      ((float4*)crow)[0] = o0; ((float4*)crow)[1] = o1;
    }
  }
}

// -------- in-place LayerNorm per 512-chunk (3 gates) + gain/bias fold -------
template<typename XT>
__global__ __launch_bounds__(256)
void ln3_kernel(XT* __restrict__ xp, const float* __restrict__ g,
                const float* __restrict__ be, const float* __restrict__ b)
{
  const size_t base = (size_t)blockIdx.x * G3_;
  const int t = threadIdx.x;
  float v[6];
  #pragma unroll
  for (int gg = 0; gg < 3; ++gg) {
    v[gg*2+0] = toF(xp[base + gg*512 + t]);
    v[gg*2+1] = toF(xp[base + gg*512 + 256 + t]);
  }
  float s0 = v[0]+v[1], q0 = v[0]*v[0]+v[1]*v[1];
  float s1 = v[2]+v[3], q1 = v[2]*v[2]+v[3]*v[3];
  float s2 = v[4]+v[5], q2 = v[4]*v[4]+v[5]*v[5];
  #pragma unroll
  for (int m = 1; m < 64; m <<= 1) {
    s0 += __shfl_xor(s0, m); q0 += __shfl_xor(q0, m);
    s1 += __shfl_xor(s1, m); q1 += __shfl_xor(q1, m);
    s2 += __shfl_xor(s2, m); q2 += __shfl_xor(q2, m);
  }
  __shared__ float red[4][6];
  __shared__ float stat[6];
  const int wid = t >> 6, lane = t & 63;
  if (lane == 0) { red[wid][0]=s0; red[wid][1]=q0; red[wid][2]=s1; red[wid][3]=q1; red[wid][4]=s2; red[wid][5]=q2; }
  __syncthreads();
  if (t < 6) stat[t] = red[0][t] + red[1][t] + red[2][t] + red[3][t];
  __syncthreads();
  #pragma unroll
  for (int gg = 0; gg < 3; ++gg) {
    const float mu  = stat[gg*2]   * (1.f/512.f);
    const float var = stat[gg*2+1] * (1.f/512.f) - mu*mu;
    const float sc  = rsqrtf(var + 1e-5f);
    #pragma unroll
    for (int u = 0; u < 2; ++u) {
      const int c = gg*512 + u*256 + t;
      storeF(&xp[base + c], (v[gg*2+u] - mu) * sc * g[c] + be[c] + b[c]);
    }
  }
}

// --------------------------- persistent scan kernel -------------------------
// Geometry: group = 8 batches; 8 groups per direction; 32 j-slice blocks per
// group. Cross-block sync: per-block step-stamped FLAGS, each in its own
// 128B cache line (relaxed agent store; NO RMW atomics, NO shared lines).
// Waiters: 32 threads poll 32 distinct lines in parallel. Bulk data moves
// via relaxed agent-scope loads/stores (L3-coherent). Ordering: s_waitcnt
// vmcnt(0) + __syncthreads before flag publish.
template<typename XT, typename HT>
__global__ __launch_bounds__(256, 2)
void scan_kernel(const XT* __restrict__ xp_f, const XT* __restrict__ xp_b,
                 const float* __restrict__ Whh_f, const float* __restrict__ Whh_b,
                 const float* __restrict__ gf, const float* __restrict__ bef, const float* __restrict__ bfv,
                 const float* __restrict__ gbv, const float* __restrict__ beb, const float* __restrict__ bbv,
                 float* __restrict__ hbuf, float* __restrict__ part,
                 unsigned* __restrict__ flags,
                 HT* __restrict__ houtF, int rsF, XT* __restrict__ houtB, int rsB,
                 float* __restrict__ outhid, int dirbase)
{
  __shared__ float hT[8][512];       // 16 KB staged h for this batch-group
  __shared__ float red[4][16][26];   // cross-wave k-slice reduction
  __shared__ float statL[48];        // [b8][gate3][sum,sumsq]
  __shared__ int sdead;

  const int bid  = blockIdx.x;
  const int gidx = dirbase*8 + (bid >> 5);   // global group 0..15
  const int dir  = gidx >> 3;
  const int bg   = gidx & 7;                 // batch group (8 batches)
  const int js   = bid & 31;                 // j slice
  const int tid  = threadIdx.x;
  const int jloc = tid & 15;
  const int pb   = tid >> 4;                 // dots: k-slice id; gates: b id
  const int wid  = tid >> 6;
  const int ksw  = (tid >> 4) & 3;
  const int j    = js*16 + jloc;

  const XT* xp   = dir ? xp_b : xp_f;
  const float* W = dir ? Whh_b : Whh_f;
  const float* gv  = dir ? gbv : gf;
  const float* bev = dir ? beb : bef;
  const float* bv  = dir ? bbv : bfv;
  float* h = hbuf + dir * (B_ * H_);
  float* pgrp = part + (size_t)gidx * (48*32);
  // flags: per group 64 flags (32 h + 32 stat), each 32 u32 = 128B line
  unsigned* hfl = flags + (size_t)gidx * 2048;
  unsigned* sfl = hfl + 1024;

  if (tid == 0) sdead = 0;

  // W slice in registers; chunk order permuted by ksw (bank-conflict spread)
  float w[3][32];
  {
    #pragma unroll
    for (int r = 0; r < 3; ++r) {
      const float* wr = W + (size_t)(r*H_ + j) * H_ + pb * 32;
      #pragma unroll
      for (int c = 0; c < 8; ++c) {
        const int p = (c + ksw*2) & 7;
        float4 f = *(const float4*)(wr + p*4);
        w[r][c*4+0] = f.x; w[r][c*4+1] = f.y; w[r][c*4+2] = f.z; w[r][c*4+3] = f.w;
      }
    }
  }
  const float gr0 = gv[j],            gr1 = gv[H_+j],               gr2 = gv[2*H_+j];
  const float gb0 = bev[j] + bv[j],   gb1 = bev[H_+j] + bv[H_+j],   gb2 = bev[2*H_+j] + bv[2*H_+j];
  __syncthreads();   // sdead visible

  for (int t = 0; t < S_; ++t) {
    // prefetch xp gate inputs for this step (independent of h -> overlaps spin)
    const int tf = dir ? (S_ - 1 - t) : t;
    float xr = 0.f, xz = 0.f, xn = 0.f;
    if (pb < 8) {
      const size_t xbase = ((size_t)tf * B_ + bg*8 + pb) * G3_;
      xr = toF(xp[xbase + j]);
      xz = toF(xp[xbase + H_ + j]);
      xn = toF(xp[xbase + 2*H_ + j]);
    }

    // ---- barrier 1: h(t-1) published by all 32 blocks ----
    if (tid < 32 && !sdead) {
      const unsigned tgt = (unsigned)t;
      int guard = 0;
      while (flagLoad(&hfl[tid*32]) < tgt) {
        __builtin_amdgcn_s_sleep(1);
        if (++guard > (1 << 22)) { sdead = 1; break; }
      }
    }
    __syncthreads();

    // stage h tile (8 b x 512 f32): coalesced 8B coherent loads, 2-way LDS banks
    {
      const int row = tid >> 5;          // 0..7
      const int seg = tid & 31;
      const ULL* hr = (const ULL*)(h + (size_t)(bg*8 + row) * H_);
      ULL v[8];
      #pragma unroll
      for (int i = 0; i < 8; ++i) v[i] = cohLoad8(hr + seg + i*32);
      ULL* dst = (ULL*)&hT[row][0];
      #pragma unroll
      for (int i = 0; i < 8; ++i) dst[seg + i*32] = v[i];
    }
    __syncthreads();

    // k-sliced dots for the 8 b of this group
    for (int b = 0; b < 8; ++b) {
      float a0 = 0.f, a1 = 0.f, a2 = 0.f;
      #pragma unroll
      for (int c = 0; c < 8; ++c) {
        const int p = (c + ksw*2) & 7;
        const float4 hv = *(const float4*)&hT[b][pb*32 + p*4];
        a0 += hv.x*w[0][c*4+0] + hv.y*w[0][c*4+1] + hv.z*w[0][c*4+2] + hv.w*w[0][c*4+3];
        a1 += hv.x*w[1][c*4+0] + hv.y*w[1][c*4+1] + hv.z*w[1][c*4+2] + hv.w*w[1][c*4+3];
        a2 += hv.x*w[2][c*4+0] + hv.y*w[2][c*4+1] + hv.z*w[2][c*4+2] + hv.w*w[2][c*4+3];
      }
      a0 += __shfl_xor(a0, 16); a0 += __shfl_xor(a0, 32);
      a1 += __shfl_xor(a1, 16); a1 += __shfl_xor(a1, 32);
      a2 += __shfl_xor(a2, 16); a2 += __shfl_xor(a2, 32);
      if (ksw == 0) {
        red[wid][jloc][b*3+0] = a0; red[wid][jloc][b*3+1] = a1; red[wid][jloc][b*3+2] = a2;
      }
    }
    __syncthreads();

    float vr = 0.f, vz = 0.f, vn = 0.f;
    if (pb < 8) {
      vr = red[0][jloc][pb*3+0]+red[1][jloc][pb*3+0]+red[2][jloc][pb*3+0]+red[3][jloc][pb*3+0];
      vz = red[0][jloc][pb*3+1]+red[1][jloc][pb*3+1]+red[2][jloc][pb*3+1]+red[3][jloc][pb*3+1];
      vn = red[0][jloc][pb*3+2]+red[1][jloc][pb*3+2]+red[2][jloc][pb*3+2]+red[3][jloc][pb*3+2];

      // LN-stat partials over this block's 16 j -> group buffer [48][32]
      float sr = vr, qr = vr*vr, sz = vz, qz = vz*vz, sn = vn, qn = vn*vn;
      #pragma unroll
      for (int m = 1; m < 16; m <<= 1) {
        sr += __shfl_xor(sr, m); qr += __shfl_xor(qr, m);
        sz += __shfl_xor(sz, m); qz += __shfl_xor(qz, m);
        sn += __shfl_xor(sn, m); qn += __shfl_xor(qn, m);
      }
      if (jloc == 0) {
        cohStore4(&pgrp[(pb*6+0)*32 + js], sr);
        cohStore4(&pgrp[(pb*6+1)*32 + js], qr);
        cohStore4(&pgrp[(pb*6+2)*32 + js], sz);
        cohStore4(&pgrp[(pb*6+3)*32 + js], qz);
        cohStore4(&pgrp[(pb*6+4)*32 + js], sn);
        cohStore4(&pgrp[(pb*6+5)*32 + js], qn);
      }
    }
    asm volatile("s_waitcnt vmcnt(0)" ::: "memory");
    __syncthreads();

    // ---- barrier 2: all 32 blocks' partials at L3 ----
    if (tid == 0) flagStore(&sfl[js*32], (unsigned)(t + 1));
    if (tid < 32 && !sdead) {
      const unsigned tgt = (unsigned)(t + 1);
      int guard = 0;
      while (flagLoad(&sfl[tid*32]) < tgt) {
        __builtin_amdgcn_s_sleep(1);
        if (++guard > (1 << 22)) { sdead = 1; break; }
      }
    }
    __syncthreads();

    // reduce 32 slot-partials -> LN stats (8 b x 3 gates x {sum, sumsq})
    if (tid < 48) {
      const ULL* prow = (const ULL*)(pgrp + tid * 32);
      float s = 0.f;
      #pragma unroll
      for (int u = 0; u < 16; ++u) {
        ULL v = cohLoad8(prow + u);
        union { ULL u64; float f[2]; } cv; cv.u64 = v;
        s += cv.f[0] + cv.f[1];
      }
      statL[tid] = s;
    }
    __syncthreads();

    // gates + h update (thread owns (b=pb<8, j))
    if (pb < 8) {
      const int ab = bg*8 + pb;
      const float mur   = statL[pb*6+0]*(1.f/512.f);
      const float var_r = statL[pb*6+1]*(1.f/512.f) - mur*mur;
      const float muz   = statL[pb*6+2]*(1.f/512.f);
      const float var_z = statL[pb*6+3]*(1.f/512.f) - muz*muz;
      const float mun   = statL[pb*6+4]*(1.f/512.f);
      const float var_n = statL[pb*6+5]*(1.f/512.f) - mun*mun;
      const float hr_ = (vr - mur) * rsqrtf(var_r + 1e-5f) * gr0 + gb0;
      const float hz_ = (vz - muz) * rsqrtf(var_z + 1e-5f) * gr1 + gb1;
      const float hn_ = (vn - mun) * rsqrtf(var_n + 1e-5f) * gr2 + gb2;
      const float rg = 1.f / (1.f + __expf(-(xr + hr_)));
      const float zg = 1.f / (1.f + __expf(-(xz + hz_)));
      const float ng = tanhf(xn + rg * hn_);
      const float hprev = hT[pb][j];
      const float hnew = (1.f - zg) * ng + zg * hprev;
      cohStore4(&h[(size_t)ab * H_ + j], hnew);
      if (dir == 0) storeF(&houtF[((size_t)tf * B_ + ab) * rsF + j], hnew);
      else          storeF(&houtB[((size_t)tf * B_ + ab) * rsB + j], hnew);
      if (t == S_ - 1) outhid[((size_t)dir * B_ + ab) * H_ + j] = hnew;
    }
    asm volatile("s_waitcnt vmcnt(0)" ::: "memory");
    __syncthreads();
    if (tid == 0) flagStore(&hfl[js*32], (unsigned)(t + 1));
  }
}

// --------------------------------- host side --------------------------------
// ctrl layout: hbuf 256KB | part 96KB | flags 128KB | pad -> 512KB total
static const size_t kCtrlBytes = 524288;
static const size_t kXpElems = (size_t)S_ * B_ * G3_;   // 100,663,296
static const size_t kHElems  = (size_t)S_ * B_ * H_;    //  33,554,432

struct Args {
  const int* src; const float* emb;
  const float *Wih_f, *Whh_f, *bih_f, *bhh_f, *gih_f, *beih_f, *ghh_f, *behh_f;
  const float *Wih_b, *Whh_b, *bih_b, *bhh_b, *gih_b, *beih_b, *ghh_b, *behh_b;
  const float *Wout, *bout;
  float* out; void* ws; hipStream_t stream;
};

// parallel: both directions' xp live (XT); h-histories alias into xp cols 0..511
template<typename XT>
static void run_parallel(const Args& a)
{
  float* hbuf = (float*)a.ws;
  float* part = hbuf + 65536;
  unsigned* flags = (unsigned*)(part + 24576);
  XT* xpf = (XT*)((char*)a.ws + kCtrlBytes);
  XT* xpb = xpf + kXpElems;
  float* outhid = a.out + kHElems;

  hipMemsetAsync(a.ws, 0, kCtrlBytes, a.stream);

  gemm_tile<XT,XT,0,0><<<dim3(512,12), dim3(256), 0, a.stream>>>(
      a.src, a.emb, (const XT*)nullptr, 0, (const XT*)nullptr, 0,
      a.Wih_f, xpf, nullptr, nullptr, G3_, E_);
  gemm_tile<XT,XT,0,0><<<dim3(512,12), dim3(256), 0, a.stream>>>(
      a.src, a.emb, (const XT*)nullptr, 0, (const XT*)nullptr, 0,
      a.Wih_b, xpb, nullptr, nullptr, G3_, E_);
  ln3_kernel<XT><<<dim3(S_*B_), dim3(256), 0, a.stream>>>(xpf, a.gih_f, a.beih_f, a.bih_f);
  ln3_kernel<XT><<<dim3(S_*B_), dim3(256), 0, a.stream>>>(xpb, a.gih_b, a.beih_b, a.bih_b);

  scan_kernel<XT,XT><<<dim3(512), dim3(256), 0, a.stream>>>(
      xpf, xpb, a.Whh_f, a.Whh_b, a.ghh_f, a.behh_f, a.bhh_f,
      a.ghh_b, a.behh_b, a.bhh_b, hbuf, part, flags,
      xpf, G3_, xpb, G3_, outhid, 0);

  gemm_tile<XT,XT,1,1><<<dim3(512,4), dim3(256), 0, a.stream>>>(
      nullptr, nullptr, xpf, G3_, xpb, G3_,
      a.Wout, (XT*)nullptr, a.out, a.bout, H_, 2*H_);
}

// sequential: one xp buffer (XT) reused; yf -> hf (HT), yb -> xp cols 0..511
template<typename XT, typename HT>
static void run_sequential(const Args& a)
{
  float* hbuf = (float*)a.ws;
  float* part = hbuf + 65536;
  unsigned* flags = (unsigned*)(part + 24576);
  XT* xp = (XT*)((char*)a.ws + kCtrlBytes);
  HT* hf = (HT*)(xp + kXpElems);
  float* outhid = a.out + kHElems;

  hipMemsetAsync(a.ws, 0, kCtrlBytes, a.stream);

  gemm_tile<XT,XT,0,0><<<dim3(512,12), dim3(256), 0, a.stream>>>(
      a.src, a.emb, (const XT*)nullptr, 0, (const XT*)nullptr, 0,
      a.Wih_f, xp, nullptr, nullptr, G3_, E_);
  ln3_kernel<XT><<<dim3(S_*B_), dim3(256), 0, a.stream>>>(xp, a.gih_f, a.beih_f, a.bih_f);
  scan_kernel<XT,HT><<<dim3(256), dim3(256), 0, a.stream>>>(
      xp, xp, a.Whh_f, a.Whh_b, a.ghh_f, a.behh_f, a.bhh_f,
      a.ghh_b, a.behh_b, a.bhh_b, hbuf, part, flags,
      hf, H_, xp, G3_, outhid, 0);

  gemm_tile<XT,XT,0,0><<<dim3(512,12), dim3(256), 0, a.stream>>>(
      a.src, a.emb, (const XT*)nullptr, 0, (const XT*)nullptr, 0,
      a.Wih_b, xp, nullptr, nullptr, G3_, E_);
  ln3_kernel<XT><<<dim3(S_*B_), dim3(256), 0, a.stream>>>(xp, a.gih_b, a.beih_b, a.bih_b);
  scan_kernel<XT,HT><<<dim3(256), dim3(256), 0, a.stream>>>(
      xp, xp, a.Whh_f, a.Whh_b, a.ghh_f, a.behh_f, a.bhh_f,
      a.ghh_b, a.behh_b, a.bhh_b, hbuf, part, flags,
      hf, H_, xp, G3_, outhid, 1);

  gemm_tile<XT,HT,1,1><<<dim3(512,4), dim3(256), 0, a.stream>>>(
      nullptr, nullptr, hf, H_, xp, G3_,
      a.Wout, (XT*)nullptr, a.out, a.bout, H_, 2*H_);
}

extern "C" void kernel_launch(void* const* d_in, const int* in_sizes, int n_in,
                              void* d_out, int out_size, void* d_ws, size_t ws_size,
                              hipStream_t stream)
{
  Args a;
  a.src    = (const int*)  d_in[0];
  a.emb    = (const float*)d_in[1];
  a.Wih_f  = (const float*)d_in[2];
  a.Whh_f  = (const float*)d_in[3];
  a.bih_f  = (const float*)d_in[4];
  a.bhh_f  = (const float*)d_in[5];
  a.gih_f  = (const float*)d_in[6];
  a.beih_f = (const float*)d_in[7];
  a.ghh_f  = (const float*)d_in[8];
  a.behh_f = (const float*)d_in[9];
  a.Wih_b  = (const float*)d_in[10];
  a.Whh_b  = (const float*)d_in[11];
  a.bih_b  = (const float*)d_in[12];
  a.bhh_b  = (const float*)d_in[13];
  a.gih_b  = (const float*)d_in[14];
  a.beih_b = (const float*)d_in[15];
  a.ghh_b  = (const float*)d_in[16];
  a.behh_b = (const float*)d_in[17];
  a.Wout   = (const float*)d_in[18];
  a.bout   = (const float*)d_in[19];
  a.out = (float*)d_out;
  a.ws = d_ws;
  a.stream = stream;

  int dev = 0, cus = 0;
  hipGetDevice(&dev);
  hipDeviceGetAttribute(&cus, hipDeviceAttributeMultiprocessorCount, dev);

  const size_t needA = kCtrlBytes + kXpElems*4 + kHElems*2;  // ~470.3 MB fp32 xp, bf16 hf
  const size_t needB = kCtrlBytes + 2*kXpElems*2;            // ~403.2 MB bf16 parallel
  const size_t needC = kCtrlBytes + kXpElems*2 + kHElems*4;  // ~336.1 MB bf16 xp, fp32 hf
  const size_t needD = kCtrlBytes + kXpElems*2 + kHElems*2;  // ~269.0 MB bf16 all

  const bool sane = (n_in == 20) && (in_sizes[0] == S_*B_) && (in_sizes[1] == 32000*E_)
                 && (in_sizes[3] == G3_*H_) && (in_sizes[18] == H_*2*H_);

  float sigv = 0.f;
  bool ran = false;
  if (!sane) {
    sigv = 20000.f + (float)n_in;
  } else if (cus < 256) {
    sigv = 100000.f + (float)cus;
  } else if (ws_size >= needA) { run_sequential<float, bf16>(a); ran = true; }
  else if (ws_size >= needB) { run_parallel<bf16>(a);            ran = true; }
  else if (ws_size >= needC) { run_sequential<bf16, float>(a);   ran = true; }
  else if (ws_size >= needD) { run_sequential<bf16, bf16>(a);    ran = true; }
  else {
    unsigned wsMB = (unsigned)(ws_size >> 20);
    if (wsMB > 998) wsMB = 998;
    sigv = 1000.f + (float)wsMB;
  }

  if (!ran) {
    signal_kernel<<<dim3(1024), dim3(256), 0, stream>>>(a.out, (long)out_size, sigv);
  } else {
    hipError_t e = hipGetLastError();
    if (e != hipSuccess) {
      signal_kernel<<<dim3(1024), dim3(256), 0, stream>>>(a.out, (long)out_size,
                                                          10000.f + (float)(int)e);
    }
  }
}